// Round 3
// baseline (677.341 us; speedup 1.0000x reference)
//
#include <hip/hip_runtime.h>
#include <hip/hip_bf16.h>

#define NROWS 8192

typedef __bf16 bf16x8 __attribute__((ext_vector_type(8)));
typedef float f32x4 __attribute__((ext_vector_type(4)));
typedef unsigned short ushort_t;
typedef unsigned int uint_t;

__device__ __forceinline__ ushort_t f2bf(float f) {
  uint_t u = __builtin_bit_cast(uint_t, f);
  u += 0x7fffu + ((u >> 16) & 1u);   // round-to-nearest-even
  return (ushort_t)(u >> 16);
}
__device__ __forceinline__ float bf2f(ushort_t h) {
  uint_t u = ((uint_t)h) << 16;
  return __builtin_bit_cast(float, u);
}

// ---------------------------------------------------------------------------
// lin: gl = relu(x@W1+b1) -> bf16 [N][F]; sq[r] = sum(bf16(gl)^2) fp32;
//      hT = (x@W2+b2)^T ones-padded -> bf16 [F+16][N] (row F = 1.0, rest 0)
// ---------------------------------------------------------------------------
template<int DIN, int F>
__global__ __launch_bounds__(256) void lin_kernel(
    const float* __restrict__ x,
    const float* __restrict__ W1, const float* __restrict__ b1,
    const float* __restrict__ W2, const float* __restrict__ b2,
    ushort_t* __restrict__ gl, float* __restrict__ sq, ushort_t* __restrict__ hT)
{
  constexpr int ROWS = 16;
  constexpr int RP   = 256 / F;      // row phases handled in parallel
  constexpr int RPT  = ROWS / RP;    // rows per thread
  __shared__ float xs[ROWS][DIN];
  __shared__ float hs[ROWS][F];
  __shared__ float sqs[ROWS];
  const int t  = threadIdx.x;
  const int r0 = blockIdx.x * ROWS;

  for (int i = t; i < ROWS * DIN; i += 256)
    xs[i / DIN][i % DIN] = x[(size_t)(r0 + i / DIN) * DIN + (i % DIN)];
  if (t < ROWS) sqs[t] = 0.f;
  __syncthreads();

  const int c = t % F, rr = t / F;
  float a1[RPT], a2[RPT];
  for (int i = 0; i < RPT; ++i) { a1[i] = b1[c]; a2[i] = b2[c]; }
  for (int k = 0; k < DIN; ++k) {
    float w1 = W1[(size_t)k * F + c];
    float w2 = W2[(size_t)k * F + c];
#pragma unroll
    for (int i = 0; i < RPT; ++i) {
      float xv = xs[rr + i * RP][k];
      a1[i] = fmaf(xv, w1, a1[i]);
      a2[i] = fmaf(xv, w2, a2[i]);
    }
  }
#pragma unroll
  for (int i = 0; i < RPT; ++i) {
    int r = rr + i * RP;
    float g = fmaxf(a1[i], 0.f);
    ushort_t gb = f2bf(g);
    gl[(size_t)(r0 + r) * F + c] = gb;
    float gf = bf2f(gb);
    atomicAdd(&sqs[r], gf * gf);
    hs[r][c] = a2[i];
  }
  __syncthreads();
  if (t < ROWS) sq[r0 + t] = sqs[t];
  if (t < F + 16) {
    ushort_t tmp[ROWS];
    if (t < F) {
#pragma unroll
      for (int r = 0; r < ROWS; ++r) tmp[r] = f2bf(hs[r][t]);
    } else {
      ushort_t v = (t == F) ? (ushort_t)0x3F80 : (ushort_t)0;  // bf16(1.0)
#pragma unroll
      for (int r = 0; r < ROWS; ++r) tmp[r] = v;
    }
    uint4* dst = (uint4*)(hT + (size_t)t * NROWS + r0);
    dst[0] = ((const uint4*)tmp)[0];
    dst[1] = ((const uint4*)tmp)[1];
  }
}

// ---------------------------------------------------------------------------
// fused: block = 4 waves sharing ONE 16-row i-strip; each wave owns a private
// 2048-row j-chunk (j-split inside the block -> NO cross-block atomics).
// Per 64-col j-tile: S = gl_i @ gl_j^T (MFMA) -> adj = sigmoid(...) -> bf16
// via swizzled wave-private LDS strip -> acc += adj @ h (ones col = deg).
// Epilogue: tree-reduce 4 waves in LDS, ONE coalesced f32 partial per block.
// Grid (512 strips, 4 j-chunks); partial[js][8192][Fp].
// ---------------------------------------------------------------------------
template<int F>
__global__ __launch_bounds__(256, 8) void fused_kernel(
    const ushort_t* __restrict__ gl, const float* __restrict__ sq,
    const ushort_t* __restrict__ hT,
    const float* __restrict__ temp_p, const float* __restrict__ theta_p,
    float* __restrict__ partial)
{
  constexpr int Fp  = F + 16;
  constexpr int NT  = Fp / 16;    // 9 (F=128) or 5 (F=64)
  constexpr int KK  = F / 32;     // 4 or 2
  constexpr int JW  = NROWS / 16; // 512 j-rows per wave
  constexpr float EPS = 1.1920929e-07f;
  constexpr int SMEM = (2 * 16 * Fp * 4 > 64 * 64 * 2) ? 2 * 16 * Fp * 4 : 64 * 64 * 2;
  __shared__ __align__(16) char smem[SMEM];
  ushort_t* adjlds = (ushort_t*)smem;   // 8 KB, XOR-swizzled, wave-private strips
  float*    red    = (float*)smem;      // aliased: used only after __syncthreads

  const int w = threadIdx.x >> 6, lane = threadIdx.x & 63;
  const int g = lane >> 4, q = lane & 15;
  const int irow  = blockIdx.x * 16;               // block's shared i-strip
  const int jbase = blockIdx.y * (4 * JW) + w * JW; // wave-private j-chunk
  const float c1 = 1.0f + *temp_p;
  const float c0 = 5.0f + *theta_p;

  // hoist A-fragments (gl_i) and sq_i for the whole j-loop
  bf16x8 aF[KK];
#pragma unroll
  for (int kk = 0; kk < KK; ++kk)
    aF[kk] = *(const bf16x8*)(gl + (size_t)(irow + q) * F + 32 * kk + 8 * g);
  float sqi[4];
#pragma unroll
  for (int r = 0; r < 4; ++r) sqi[r] = sq[irow + 4 * g + r];

  f32x4 acc[NT];
#pragma unroll
  for (int i = 0; i < NT; ++i) acc[i] = (f32x4){0.f, 0.f, 0.f, 0.f};

  for (int j0 = jbase; j0 < jbase + JW; j0 += 64) {
    // ---- phase A: S tile [16][64]
    f32x4 s[4];
    float sqj[4];
#pragma unroll
    for (int tt = 0; tt < 4; ++tt) {
      sqj[tt] = sq[j0 + 16 * tt + q];
      f32x4 cacc = (f32x4){0.f, 0.f, 0.f, 0.f};
#pragma unroll
      for (int kk = 0; kk < KK; ++kk) {
        bf16x8 b = *(const bf16x8*)(gl + (size_t)(j0 + 16 * tt + q) * F + 32 * kk + 8 * g);
        cacc = __builtin_amdgcn_mfma_f32_16x16x32_bf16(aF[kk], b, cacc, 0, 0, 0);
      }
      s[tt] = cacc;
    }
    // ---- elementwise: diff -> dist -> sigmoid -> bf16 adj into LDS
#pragma unroll
    for (int tt = 0; tt < 4; ++tt) {
#pragma unroll
      for (int r = 0; r < 4; ++r) {
        float diff = fmaxf(sqi[r] + sqj[tt] - 2.f * s[tt][r], 0.f);
        float arg = c0;
        if (diff != 0.f) arg = c0 - c1 * __builtin_amdgcn_sqrtf(diff + EPS);
        float adjv = __builtin_amdgcn_rcpf(1.f + __expf(-arg));
        int row = 16 * w + 4 * g + r;
        int col = 16 * tt + q;
        int byte = row * 128 + ((col * 2) ^ ((row & 7) << 4));
        *(ushort_t*)((char*)adjlds + byte) = f2bf(adjv);
      }
    }
    // RAW fence: wave-private strip, wave-level sync only (rule #18)
    asm volatile("s_waitcnt lgkmcnt(0)" ::: "memory");
    __builtin_amdgcn_sched_barrier(0);
    // ---- phase B: acc += adj[16][64] @ h[64][Fp]
#pragma unroll
    for (int kk2 = 0; kk2 < 2; ++kk2) {
      int row = 16 * w + q;
      int byte = row * 128 + ((64 * kk2 + 16 * g) ^ ((row & 7) << 4));
      bf16x8 aP = *(const bf16x8*)((char*)adjlds + byte);
#pragma unroll
      for (int t2 = 0; t2 < NT; ++t2) {
        bf16x8 b = *(const bf16x8*)(hT + (size_t)(16 * t2 + q) * NROWS + j0 + 32 * kk2 + 8 * g);
        acc[t2] = __builtin_amdgcn_mfma_f32_16x16x32_bf16(aP, b, acc[t2], 0, 0, 0);
      }
    }
    // WAR fence: ds_reads complete before next iteration's writes
    asm volatile("s_waitcnt lgkmcnt(0)" ::: "memory");
    __builtin_amdgcn_sched_barrier(0);
  }

  // ---- epilogue: tree-reduce the 4 waves' acc in LDS (aliased w/ adjlds),
  // then one coalesced non-atomic partial write per block.
  __syncthreads();
  if (w == 1 || w == 3) {
    float* dst = red + (size_t)(w >> 1) * 16 * Fp;
#pragma unroll
    for (int t2 = 0; t2 < NT; ++t2)
#pragma unroll
      for (int r = 0; r < 4; ++r)
        dst[(4 * g + r) * Fp + 16 * t2 + q] = acc[t2][r];
  }
  __syncthreads();
  if (w == 0 || w == 2) {
    const float* srcp = red + (size_t)(w >> 1) * 16 * Fp;
#pragma unroll
    for (int t2 = 0; t2 < NT; ++t2)
#pragma unroll
      for (int r = 0; r < 4; ++r)
        acc[t2][r] += srcp[(4 * g + r) * Fp + 16 * t2 + q];
  }
  __syncthreads();
  if (w == 2) {
#pragma unroll
    for (int t2 = 0; t2 < NT; ++t2)
#pragma unroll
      for (int r = 0; r < 4; ++r)
        red[(4 * g + r) * Fp + 16 * t2 + q] = acc[t2][r];
  }
  __syncthreads();
  if (w == 0) {
    float* op = partial + ((size_t)blockIdx.y * NROWS + irow) * Fp;
#pragma unroll
    for (int t2 = 0; t2 < NT; ++t2)
#pragma unroll
      for (int r = 0; r < 4; ++r)
        op[(4 * g + r) * Fp + 16 * t2 + q] =
            acc[t2][r] + red[(4 * g + r) * Fp + 16 * t2 + q];
  }
}

// x_next = relu(sum_js(partial col c) / sum_js(partial col F))
template<int F, bool RELU>
__global__ __launch_bounds__(256) void reduce_div_kernel(
    const float* __restrict__ partial, float* __restrict__ out)
{
  int idx = blockIdx.x * 256 + threadIdx.x;
  int r = idx / F, c = idx % F;
  size_t base = (size_t)r * (F + 16);
  size_t stride = (size_t)NROWS * (F + 16);
  float s = 0.f, d = 0.f;
#pragma unroll
  for (int js = 0; js < 4; ++js) {
    s += partial[js * stride + base + c];
    d += partial[js * stride + base + F];
  }
  float v = s / d;
  if (RELU) v = fmaxf(v, 0.f);
  out[idx] = v;
}

// out = softmax(sum_js(partial)/deg) rowwise; one wave per row
__global__ __launch_bounds__(64) void reduce_softmax_kernel(
    const float* __restrict__ partial, float* __restrict__ out)
{
  int r = blockIdx.x, c = threadIdx.x;
  size_t base = (size_t)r * 80;
  size_t stride = (size_t)NROWS * 80;
  float v = 0.f, d = 0.f;
#pragma unroll
  for (int js = 0; js < 4; ++js) {
    v += partial[js * stride + base + c];
    d += partial[js * stride + base + 64];
  }
  v /= d;
  float m = v;
  for (int o = 32; o > 0; o >>= 1) m = fmaxf(m, __shfl_xor(m, o, 64));
  float e = __expf(v - m);
  float s = e;
  for (int o = 32; o > 0; o >>= 1) s += __shfl_xor(s, o, 64);
  out[(size_t)r * 64 + c] = e / s;
}

extern "C" void kernel_launch(void* const* d_in, const int* in_sizes, int n_in,
                              void* d_out, int out_size, void* d_ws, size_t ws_size,
                              hipStream_t stream) {
  const float* feat  = (const float*)d_in[0];
  const float* Wgl0  = (const float*)d_in[6];
  const float* bgl0  = (const float*)d_in[7];
  const float* Wgnn0 = (const float*)d_in[8];
  const float* bgnn0 = (const float*)d_in[9];
  const float* Wgl1  = (const float*)d_in[10];
  const float* bgl1  = (const float*)d_in[11];
  const float* Wgnn1 = (const float*)d_in[12];
  const float* bgnn1 = (const float*)d_in[13];
  const float* temp  = (const float*)d_in[14];
  const float* theta = (const float*)d_in[15];
  float* out = (float*)d_out;

  char* ws = (char*)d_ws;
  size_t off = 0;
  auto alloc = [&](size_t bytes) {
    char* p = ws + off;
    off = (off + bytes + 255) & ~(size_t)255;
    return p;
  };
  float*    par0 = (float*)alloc(4ull * NROWS * 144 * 4);  // 18.9 MB
  float*    par1 = (float*)alloc(4ull * NROWS * 80 * 4);   // 10.5 MB
  float*    x1   = (float*)alloc(8192ull * 128 * 4);
  ushort_t* gl0  = (ushort_t*)alloc(8192ull * 128 * 2);
  ushort_t* gl1  = (ushort_t*)alloc(8192ull * 64 * 2);
  ushort_t* h0T  = (ushort_t*)alloc(144ull * 8192 * 2);
  ushort_t* h1T  = (ushort_t*)alloc(80ull * 8192 * 2);
  float*    sq0  = (float*)alloc(8192ull * 4);
  float*    sq1  = (float*)alloc(8192ull * 4);

  lin_kernel<256, 128><<<512, 256, 0, stream>>>(feat, Wgl0, bgl0, Wgnn0, bgnn0, gl0, sq0, h0T);
  fused_kernel<128><<<dim3(512, 4), 256, 0, stream>>>(gl0, sq0, h0T, temp, theta, par0);
  reduce_div_kernel<128, true><<<(8192 * 128) / 256, 256, 0, stream>>>(par0, x1);

  lin_kernel<128, 64><<<512, 256, 0, stream>>>(x1, Wgl1, bgl1, Wgnn1, bgnn1, gl1, sq1, h1T);
  fused_kernel<64><<<dim3(512, 4), 256, 0, stream>>>(gl1, sq1, h1T, temp, theta, par1);
  reduce_softmax_kernel<<<8192, 64, 0, stream>>>(par1, out);
}

// Round 4
// 535.327 us; speedup vs baseline: 1.2653x; 1.2653x over previous
//
#include <hip/hip_runtime.h>
#include <hip/hip_bf16.h>

#define NROWS 8192

typedef __bf16 bf16x8 __attribute__((ext_vector_type(8)));
typedef float f32x4 __attribute__((ext_vector_type(4)));
typedef unsigned short ushort_t;
typedef unsigned int uint_t;

__device__ __forceinline__ ushort_t f2bf(float f) {
  uint_t u = __builtin_bit_cast(uint_t, f);
  u += 0x7fffu + ((u >> 16) & 1u);   // round-to-nearest-even
  return (ushort_t)(u >> 16);
}
__device__ __forceinline__ float bf2f(ushort_t h) {
  uint_t u = ((uint_t)h) << 16;
  return __builtin_bit_cast(float, u);
}

// ---------------------------------------------------------------------------
// lin: gl = relu(x@W1+b1) -> bf16 [N][F]; sq[r] = sum(bf16(gl)^2) fp32;
//      hT = (x@W2+b2)^T ones-padded -> bf16 [F+16][N] (row F = 1.0, rest 0)
// ---------------------------------------------------------------------------
template<int DIN, int F>
__global__ __launch_bounds__(256) void lin_kernel(
    const float* __restrict__ x,
    const float* __restrict__ W1, const float* __restrict__ b1,
    const float* __restrict__ W2, const float* __restrict__ b2,
    ushort_t* __restrict__ gl, float* __restrict__ sq, ushort_t* __restrict__ hT)
{
  constexpr int ROWS = 16;
  constexpr int RP   = 256 / F;      // row phases handled in parallel
  constexpr int RPT  = ROWS / RP;    // rows per thread
  __shared__ float xs[ROWS][DIN];
  __shared__ float hs[ROWS][F];
  __shared__ float sqs[ROWS];
  const int t  = threadIdx.x;
  const int r0 = blockIdx.x * ROWS;

  for (int i = t; i < ROWS * DIN; i += 256)
    xs[i / DIN][i % DIN] = x[(size_t)(r0 + i / DIN) * DIN + (i % DIN)];
  if (t < ROWS) sqs[t] = 0.f;
  __syncthreads();

  const int c = t % F, rr = t / F;
  float a1[RPT], a2[RPT];
  for (int i = 0; i < RPT; ++i) { a1[i] = b1[c]; a2[i] = b2[c]; }
  for (int k = 0; k < DIN; ++k) {
    float w1 = W1[(size_t)k * F + c];
    float w2 = W2[(size_t)k * F + c];
#pragma unroll
    for (int i = 0; i < RPT; ++i) {
      float xv = xs[rr + i * RP][k];
      a1[i] = fmaf(xv, w1, a1[i]);
      a2[i] = fmaf(xv, w2, a2[i]);
    }
  }
#pragma unroll
  for (int i = 0; i < RPT; ++i) {
    int r = rr + i * RP;
    float g = fmaxf(a1[i], 0.f);
    ushort_t gb = f2bf(g);
    gl[(size_t)(r0 + r) * F + c] = gb;
    float gf = bf2f(gb);
    atomicAdd(&sqs[r], gf * gf);
    hs[r][c] = a2[i];
  }
  __syncthreads();
  if (t < ROWS) sq[r0 + t] = sqs[t];
  if (t < F + 16) {
    ushort_t tmp[ROWS];
    if (t < F) {
#pragma unroll
      for (int r = 0; r < ROWS; ++r) tmp[r] = f2bf(hs[r][t]);
    } else {
      ushort_t v = (t == F) ? (ushort_t)0x3F80 : (ushort_t)0;  // bf16(1.0)
#pragma unroll
      for (int r = 0; r < ROWS; ++r) tmp[r] = v;
    }
    uint4* dst = (uint4*)(hT + (size_t)t * NROWS + r0);
    dst[0] = ((const uint4*)tmp)[0];
    dst[1] = ((const uint4*)tmp)[1];
  }
}

// ---------------------------------------------------------------------------
// fused: block = 4 waves = one 64-row i-tile, each wave privately owns a
// 16-row strip. Per 64-col j-tile: S = gl_i @ gl_j^T (MFMA) -> adj =
// sigmoid((1+temp)*dist + 5+theta) -> bf16 via swizzled wave-private LDS ->
// acc += adj @ h (ones col = deg). j-split JS=8 across blocks; each wave
// writes its own partial rows directly (disjoint -> NO atomics, no red tree).
// partial[js][NROWS][Fp]. VGPR kept natural (no min-occupancy bound; R3
// lesson: forcing 8 waves/EU spilled acc in-loop -> 1 GB scratch traffic).
// ---------------------------------------------------------------------------
template<int F>
__global__ __launch_bounds__(256) void fused_kernel(
    const ushort_t* __restrict__ gl, const float* __restrict__ sq,
    const ushort_t* __restrict__ hT,
    const float* __restrict__ temp_p, const float* __restrict__ theta_p,
    float* __restrict__ partial)
{
  constexpr int Fp  = F + 16;
  constexpr int NT  = Fp / 16;    // 9 (F=128) or 5 (F=64)
  constexpr int KK  = F / 32;     // 4 or 2
  constexpr int JS  = 8;
  constexpr int JCH = NROWS / JS; // 1024 j-rows per block
  constexpr float EPS = 1.1920929e-07f;
  __shared__ __align__(16) ushort_t adjlds[64 * 64];  // 8 KB, XOR-swizzled

  const int w = threadIdx.x >> 6, lane = threadIdx.x & 63;
  const int g = lane >> 4, q = lane & 15;
  const int irow  = blockIdx.x * 64 + 16 * w;   // this wave's private 16 rows
  const int jbase = blockIdx.y * JCH;
  const float c1 = 1.0f + *temp_p;
  const float c0 = 5.0f + *theta_p;

  // hoist A-fragments (gl_i) and sq_i for the whole j-loop
  bf16x8 aF[KK];
#pragma unroll
  for (int kk = 0; kk < KK; ++kk)
    aF[kk] = *(const bf16x8*)(gl + (size_t)(irow + q) * F + 32 * kk + 8 * g);
  float sqi[4];
#pragma unroll
  for (int r = 0; r < 4; ++r) sqi[r] = sq[irow + 4 * g + r];

  f32x4 acc[NT];
#pragma unroll
  for (int i = 0; i < NT; ++i) acc[i] = (f32x4){0.f, 0.f, 0.f, 0.f};

  for (int j0 = jbase; j0 < jbase + JCH; j0 += 64) {
    // ---- phase A: S tile [16][64]
    f32x4 s[4];
    float sqj[4];
#pragma unroll
    for (int tt = 0; tt < 4; ++tt) {
      sqj[tt] = sq[j0 + 16 * tt + q];
      f32x4 cacc = (f32x4){0.f, 0.f, 0.f, 0.f};
#pragma unroll
      for (int kk = 0; kk < KK; ++kk) {
        bf16x8 b = *(const bf16x8*)(gl + (size_t)(j0 + 16 * tt + q) * F + 32 * kk + 8 * g);
        cacc = __builtin_amdgcn_mfma_f32_16x16x32_bf16(aF[kk], b, cacc, 0, 0, 0);
      }
      s[tt] = cacc;
    }
    // ---- elementwise: diff -> dist -> sigmoid -> bf16 adj into LDS
#pragma unroll
    for (int tt = 0; tt < 4; ++tt) {
#pragma unroll
      for (int r = 0; r < 4; ++r) {
        float diff = fmaxf(sqi[r] + sqj[tt] - 2.f * s[tt][r], 0.f);
        float arg = c0;
        if (diff != 0.f) arg = c0 - c1 * __builtin_amdgcn_sqrtf(diff + EPS);
        float adjv = __builtin_amdgcn_rcpf(1.f + __expf(-arg));
        int row = 16 * w + 4 * g + r;
        int col = 16 * tt + q;
        int byte = row * 128 + ((col * 2) ^ ((row & 7) << 4));
        *(ushort_t*)((char*)adjlds + byte) = f2bf(adjv);
      }
    }
    // RAW fence (cross-lane, same wave): writes visible before reads.
    // No sched_barrier: let the scheduler pipeline global loads across it.
    asm volatile("s_waitcnt lgkmcnt(0)" ::: "memory");
    // ---- phase B: acc += adj[16][64] @ h[64][Fp]
#pragma unroll
    for (int kk2 = 0; kk2 < 2; ++kk2) {
      int row = 16 * w + q;
      int byte = row * 128 + ((64 * kk2 + 16 * g) ^ ((row & 7) << 4));
      bf16x8 aP = *(const bf16x8*)((char*)adjlds + byte);
#pragma unroll
      for (int t2 = 0; t2 < NT; ++t2) {
        bf16x8 b = *(const bf16x8*)(hT + (size_t)(16 * t2 + q) * NROWS + j0 + 32 * kk2 + 8 * g);
        acc[t2] = __builtin_amdgcn_mfma_f32_16x16x32_bf16(aP, b, acc[t2], 0, 0, 0);
      }
    }
    // WAR fence: this iter's ds_reads done before next iter's ds_writes.
    asm volatile("s_waitcnt lgkmcnt(0)" ::: "memory");
  }

  // ---- epilogue: each wave owns rows irow..irow+15 -> direct disjoint store
  float* op = partial + ((size_t)blockIdx.y * NROWS + irow) * Fp;
#pragma unroll
  for (int t2 = 0; t2 < NT; ++t2)
#pragma unroll
    for (int r = 0; r < 4; ++r)
      op[(size_t)(4 * g + r) * Fp + 16 * t2 + q] = acc[t2][r];
}

// x_next = relu(sum_js(partial col c) / sum_js(partial col F))
template<int F, bool RELU>
__global__ __launch_bounds__(256) void reduce_div_kernel(
    const float* __restrict__ partial, float* __restrict__ out)
{
  int idx = blockIdx.x * 256 + threadIdx.x;
  int r = idx / F, c = idx % F;
  size_t base = (size_t)r * (F + 16);
  size_t stride = (size_t)NROWS * (F + 16);
  float s = 0.f, d = 0.f;
#pragma unroll
  for (int js = 0; js < 8; ++js) {
    s += partial[js * stride + base + c];
    d += partial[js * stride + base + F];
  }
  float v = s / d;
  if (RELU) v = fmaxf(v, 0.f);
  out[idx] = v;
}

// out = softmax(sum_js(partial)/deg) rowwise; one wave per row
__global__ __launch_bounds__(64) void reduce_softmax_kernel(
    const float* __restrict__ partial, float* __restrict__ out)
{
  int r = blockIdx.x, c = threadIdx.x;
  size_t base = (size_t)r * 80;
  size_t stride = (size_t)NROWS * 80;
  float v = 0.f, d = 0.f;
#pragma unroll
  for (int js = 0; js < 8; ++js) {
    v += partial[js * stride + base + c];
    d += partial[js * stride + base + 64];
  }
  v /= d;
  float m = v;
  for (int o = 32; o > 0; o >>= 1) m = fmaxf(m, __shfl_xor(m, o, 64));
  float e = __expf(v - m);
  float s = e;
  for (int o = 32; o > 0; o >>= 1) s += __shfl_xor(s, o, 64);
  out[(size_t)r * 64 + c] = e / s;
}

extern "C" void kernel_launch(void* const* d_in, const int* in_sizes, int n_in,
                              void* d_out, int out_size, void* d_ws, size_t ws_size,
                              hipStream_t stream) {
  const float* feat  = (const float*)d_in[0];
  const float* Wgl0  = (const float*)d_in[6];
  const float* bgl0  = (const float*)d_in[7];
  const float* Wgnn0 = (const float*)d_in[8];
  const float* bgnn0 = (const float*)d_in[9];
  const float* Wgl1  = (const float*)d_in[10];
  const float* bgl1  = (const float*)d_in[11];
  const float* Wgnn1 = (const float*)d_in[12];
  const float* bgnn1 = (const float*)d_in[13];
  const float* temp  = (const float*)d_in[14];
  const float* theta = (const float*)d_in[15];
  float* out = (float*)d_out;

  char* ws = (char*)d_ws;
  size_t off = 0;
  auto alloc = [&](size_t bytes) {
    char* p = ws + off;
    off = (off + bytes + 255) & ~(size_t)255;
    return p;
  };
  float*    par0 = (float*)alloc(8ull * NROWS * 144 * 4);  // 37.7 MB
  float*    par1 = par0;  // aliased: par0 is consumed before fused<64> runs
  float*    x1   = (float*)alloc(8192ull * 128 * 4);
  ushort_t* gl0  = (ushort_t*)alloc(8192ull * 128 * 2);
  ushort_t* gl1  = (ushort_t*)alloc(8192ull * 64 * 2);
  ushort_t* h0T  = (ushort_t*)alloc(144ull * 8192 * 2);
  ushort_t* h1T  = (ushort_t*)alloc(80ull * 8192 * 2);
  float*    sq0  = (float*)alloc(8192ull * 4);
  float*    sq1  = (float*)alloc(8192ull * 4);

  lin_kernel<256, 128><<<512, 256, 0, stream>>>(feat, Wgl0, bgl0, Wgnn0, bgnn0, gl0, sq0, h0T);
  fused_kernel<128><<<dim3(128, 8), 256, 0, stream>>>(gl0, sq0, h0T, temp, theta, par0);
  reduce_div_kernel<128, true><<<(8192 * 128) / 256, 256, 0, stream>>>(par0, x1);

  lin_kernel<128, 64><<<512, 256, 0, stream>>>(x1, Wgl1, bgl1, Wgnn1, bgnn1, gl1, sq1, h1T);
  fused_kernel<64><<<dim3(128, 8), 256, 0, stream>>>(gl1, sq1, h1T, temp, theta, par1);
  reduce_softmax_kernel<<<8192, 64, 0, stream>>>(par1, out);
}